// Round 4
// baseline (252.878 us; speedup 1.0000x reference)
//
#include <hip/hip_runtime.h>
#include <stdint.h>

// LIF spike encoder — fp32 output, layout (B, T, N).
//
// Evidence model (rounds 0-3):
//  - inputs fp32 (round-3 on-device dtype detector took the fp32 path:
//    absmax byte-identical to round 1)
//  - d_out is FP32 (reference output dtype float32; the "(bf16)" in the test
//    label is the expected-array storage, floor_eps_k=8 / threshold 0.0994)
//  - under fp32-out decoding, round-1's 5.984375 = max over ~131072 random
//    analog/analog collisions (pred ~6.0) and round-2's 4.96875 = max|ref|:
//    both match layout (B,T,N) + fp32 writes.
//
// Numerics (must reproduce np/XLA fp32 bit-for-bit to avoid spike flips):
//  - I[b,n] = ascending-k fp32 FMA chain (dense t=1)
//  - sparse steps: ordered fp32 adds over SORTED spike indices — identical to
//    the dense chain since fmaf(0,w,a)==a, fmaf(1,w,a)==rn(a+w)
//  - V: d=alpha*V (1 rounding); *(1-Z) exact (0/1 select); +I (1 rounding);
//    asm barrier forbids fma-contraction of alpha*V into the +I
//  - Z = V > 1.0f strict; output spike values 1.0f/0.0f; frame 0 = raw x
//  - dead network (no spikes in a row) -> remaining frames exactly 0 ->
//    bulk zero-fill and exit.

#define BATCHSZ 256
#define NU      2048
#define TSTEPS  128
#define BLK     1024
#define NWAVES  (BLK / 64)

__global__ __launch_bounds__(BLK) void lif_spike_encoder(
    const float* __restrict__ x,
    const float* __restrict__ W,
    float* __restrict__ out)
{
    const int b    = blockIdx.x;
    const int tid  = threadIdx.x;
    const int lane = tid & 63;
    const int wid  = tid >> 6;

    __shared__ float         s_x[NU];
    __shared__ int           s_idx[NU];
    __shared__ unsigned char s_flag[NU];
    __shared__ int           s_wsum[NWAVES];
    __shared__ int           s_cnt;

    const int n0 = tid;
    const int n1 = tid + BLK;

    float* outb = out + (size_t)b * TSTEPS * NU;   // (B, T, N)

    // ---- stage x row into LDS; frame 0 = raw fp32 x
    {
        float x0 = x[(size_t)b * NU + n0];
        float x1 = x[(size_t)b * NU + n1];
        s_x[n0] = x0;
        s_x[n1] = x1;
        outb[n0] = x0;
        outb[n1] = x1;
    }
    __syncthreads();

    // ---- t=1 dense: I = x @ W, ascending-k fp32 FMA chain
    float I0 = 0.0f, I1 = 0.0f;
    {
        const float* Wc = W + tid;
        #pragma unroll 8
        for (int k = 0; k < NU; ++k) {
            float xk = s_x[k];                 // LDS broadcast
            const float* wr = Wc + (size_t)k * NU;
            I0 = __builtin_fmaf(xk, wr[0],   I0);
            I1 = __builtin_fmaf(xk, wr[BLK], I1);
        }
    }

    float V0 = 0.0f, V1 = 0.0f;
    int   z0 = 0,    z1 = 0;

    for (int t = 1; t < TSTEPS; ++t) {
        if (t >= 2) {
            // ---- ascending spike index list (wave scan + wave offsets)
            int f0 = s_flag[2 * tid];
            int f1 = s_flag[2 * tid + 1];
            int c  = f0 + f1;
            int v  = c;
            #pragma unroll
            for (int d = 1; d < 64; d <<= 1) {
                int o = __shfl_up(v, d);
                if (lane >= d) v += o;
            }
            if (lane == 63) s_wsum[wid] = v;
            __syncthreads();
            int base = 0;
            #pragma unroll
            for (int w = 0; w < NWAVES; ++w) base += (w < wid) ? s_wsum[w] : 0;
            int off = base + v - c;            // exclusive prefix
            if (f0) s_idx[off++] = 2 * tid;
            if (f1) s_idx[off]   = 2 * tid + 1;
            if (tid == BLK - 1) s_cnt = base + v;
            __syncthreads();

            int cnt = s_cnt;
            if (cnt == 0) {
                // dead network: all remaining frames exactly zero (fp32)
                size_t elems  = (size_t)(TSTEPS - t) * NU;   // floats
                float4* p     = (float4*)(outb + (size_t)t * NU);
                int     chunks = (int)(elems / 4);
                float4  zz; zz.x = zz.y = zz.z = zz.w = 0.0f;
                for (int i = tid; i < chunks; i += BLK) p[i] = zz;
                return;
            }

            // ---- sparse I: ordered fp32 adds over sorted spiking rows
            I0 = 0.0f; I1 = 0.0f;
            const float* Wc = W + tid;
            int i = 0;
            for (; i + 2 <= cnt; i += 2) {
                const float* r0 = Wc + (size_t)s_idx[i]     * NU;
                const float* r1 = Wc + (size_t)s_idx[i + 1] * NU;
                float a0 = r0[0], b0 = r0[BLK];
                float a1 = r1[0], b1 = r1[BLK];
                I0 += a0; I0 += a1;            // order preserved
                I1 += b0; I1 += b1;
            }
            for (; i < cnt; ++i) {
                const float* r = Wc + (size_t)s_idx[i] * NU;
                I0 += r[0];
                I1 += r[BLK];
            }
        }

        // ---- V update + threshold, op-by-op as the reference
        float d0 = 0.90483741803595952f * V0;   // one rounding
        float d1 = 0.90483741803595952f * V1;
        asm volatile("" : "+v"(d0), "+v"(d1));  // forbid fma-contraction
        float nv0 = (z0 ? 0.0f : d0) + I0;      // one rounding
        float nv1 = (z1 ? 0.0f : d1) + I1;
        V0 = nv0; V1 = nv1;
        z0 = nv0 > 1.0f;
        z1 = nv1 > 1.0f;

        float* po = outb + (size_t)t * NU;
        po[n0] = z0 ? 1.0f : 0.0f;
        po[n1] = z1 ? 1.0f : 0.0f;
        s_flag[n0] = (unsigned char)z0;
        s_flag[n1] = (unsigned char)z1;
        __syncthreads();
    }
}

extern "C" void kernel_launch(void* const* d_in, const int* in_sizes, int n_in,
                              void* d_out, int out_size, void* d_ws, size_t ws_size,
                              hipStream_t stream) {
    const float* x = (const float*)d_in[0];   // (256, 2048) fp32
    const float* W = (const float*)d_in[1];   // (2048, 2048) fp32
    if (n_in >= 2 && in_sizes[0] == NU * NU && in_sizes[1] == BATCHSZ * NU) {
        // defensive: swap if harness ordered (W, x)
        const float* t = x; x = W; W = t;
    }
    float* out = (float*)d_out;               // (B=256, T=128, N=2048) fp32

    hipLaunchKernelGGL(lif_spike_encoder, dim3(BATCHSZ), dim3(BLK), 0, stream,
                       x, W, out);
}

// Round 5
// 248.394 us; speedup vs baseline: 1.0181x; 1.0181x over previous
//
#include <hip/hip_runtime.h>
#include <stdint.h>

// LIF spike encoder — two-phase, bit-exact fp32. PASSED round 4 (absmax 0.0)
// as a single fused kernel at 320 us; this round splits the dense t=1 GEMM
// out of the per-row block so W isn't streamed 256x through L2.
//
//   x: (256, 2048) fp32   W: (2048, 2048) fp32   out: (B=256,T=128,N=2048) fp32
//
// Phase A: V1 = x @ W as an LDS-tiled GEMM -> d_ws (2 MB). Per output element
//   the accumulation is ONE register, k ascending 0..2047 -> bit-identical
//   chain to the round-4 kernel (which passed with absmax 0.0).
// Phase B: per-row recurrence from t=2 (unchanged logic): sorted spike list,
//   ordered sparse adds (== dense chain exactly), op-by-op V update,
//   dead-network early exit with bulk zero-fill.

#define BATCHSZ 256
#define NU      2048
#define TSTEPS  128
#define BLK     1024
#define NWAVES  (BLK / 64)

// ---------------- Phase A: dense GEMM (t=1), bit-exact chain ----------------
// BM=16, BN=128, BK=128; 128 threads; 4x4 micro-tile; grid 16x16 = 256 blocks.
#define A_BM 16
#define A_BN 128
#define A_BK 128

__global__ __launch_bounds__(128) void lif_dense_v1(
    const float* __restrict__ x,
    const float* __restrict__ W,
    float* __restrict__ ws)
{
    __shared__ float s_xT[A_BK][A_BM];      // [k][m], 8 KB

    const int tid = threadIdx.x;
    const int n0  = blockIdx.x * A_BN;
    const int m0  = blockIdx.y * A_BM;
    const int ng  = tid & 31;               // n-group 0..31
    const int mg  = tid >> 5;               // m-group 0..3
    const int n   = n0 + ng * 4;
    const int m   = mg * 4;

    const int lm = tid >> 3;                // staging: m 0..15
    const int lk = (tid & 7) * 16;          // staging: k-offset 0..112

    float acc[4][4];
    #pragma unroll
    for (int i = 0; i < 4; ++i)
        #pragma unroll
        for (int j = 0; j < 4; ++j) acc[i][j] = 0.0f;

    for (int kb = 0; kb < NU; kb += A_BK) {
        // stage x[m0+lm][kb+lk .. kb+lk+15] -> s_xT[lk..lk+15][lm]
        const float4* xr = (const float4*)(x + (size_t)(m0 + lm) * NU + kb + lk);
        float4 v0 = xr[0], v1 = xr[1], v2 = xr[2], v3 = xr[3];
        __syncthreads();                     // protect previous tile's readers
        s_xT[lk +  0][lm] = v0.x; s_xT[lk +  1][lm] = v0.y;
        s_xT[lk +  2][lm] = v0.z; s_xT[lk +  3][lm] = v0.w;
        s_xT[lk +  4][lm] = v1.x; s_xT[lk +  5][lm] = v1.y;
        s_xT[lk +  6][lm] = v1.z; s_xT[lk +  7][lm] = v1.w;
        s_xT[lk +  8][lm] = v2.x; s_xT[lk +  9][lm] = v2.y;
        s_xT[lk + 10][lm] = v2.z; s_xT[lk + 11][lm] = v2.w;
        s_xT[lk + 12][lm] = v3.x; s_xT[lk + 13][lm] = v3.y;
        s_xT[lk + 14][lm] = v3.z; s_xT[lk + 15][lm] = v3.w;
        __syncthreads();

        const float* wp = W + (size_t)kb * NU + n;
        #pragma unroll 8
        for (int k = 0; k < A_BK; ++k) {
            float4 xv = *(const float4*)&s_xT[k][m];
            float4 wv = *(const float4*)wp;              // W[kb+k][n..n+3]
            acc[0][0] = __builtin_fmaf(xv.x, wv.x, acc[0][0]);
            acc[0][1] = __builtin_fmaf(xv.x, wv.y, acc[0][1]);
            acc[0][2] = __builtin_fmaf(xv.x, wv.z, acc[0][2]);
            acc[0][3] = __builtin_fmaf(xv.x, wv.w, acc[0][3]);
            acc[1][0] = __builtin_fmaf(xv.y, wv.x, acc[1][0]);
            acc[1][1] = __builtin_fmaf(xv.y, wv.y, acc[1][1]);
            acc[1][2] = __builtin_fmaf(xv.y, wv.z, acc[1][2]);
            acc[1][3] = __builtin_fmaf(xv.y, wv.w, acc[1][3]);
            acc[2][0] = __builtin_fmaf(xv.z, wv.x, acc[2][0]);
            acc[2][1] = __builtin_fmaf(xv.z, wv.y, acc[2][1]);
            acc[2][2] = __builtin_fmaf(xv.z, wv.z, acc[2][2]);
            acc[2][3] = __builtin_fmaf(xv.z, wv.w, acc[2][3]);
            acc[3][0] = __builtin_fmaf(xv.w, wv.x, acc[3][0]);
            acc[3][1] = __builtin_fmaf(xv.w, wv.y, acc[3][1]);
            acc[3][2] = __builtin_fmaf(xv.w, wv.z, acc[3][2]);
            acc[3][3] = __builtin_fmaf(xv.w, wv.w, acc[3][3]);
            wp += NU;
        }
    }

    #pragma unroll
    for (int i = 0; i < 4; ++i) {
        float4 o; o.x = acc[i][0]; o.y = acc[i][1]; o.z = acc[i][2]; o.w = acc[i][3];
        *(float4*)&ws[(size_t)(m0 + m + i) * NU + n] = o;
    }
}

// ---------------- Phase B: recurrence from t=2 ----------------
__global__ __launch_bounds__(BLK) void lif_recurrence(
    const float* __restrict__ x,
    const float* __restrict__ W,
    const float* __restrict__ V1,
    float* __restrict__ out)
{
    const int b    = blockIdx.x;
    const int tid  = threadIdx.x;
    const int lane = tid & 63;
    const int wid  = tid >> 6;

    __shared__ int           s_idx[NU];      // spiking row offsets (k*NU)
    __shared__ unsigned char s_flag[NU];
    __shared__ int           s_wsum[NWAVES];
    __shared__ int           s_cnt;

    const int n0 = tid;
    const int n1 = tid + BLK;

    float* outb = out + (size_t)b * TSTEPS * NU;   // (B, T, N)

    // frame 0 = x; V from ws; frame 1 = threshold(V1)
    float V0, V1r;
    int   z0, z1;
    {
        float x0 = x[(size_t)b * NU + n0];
        float x1 = x[(size_t)b * NU + n1];
        outb[n0] = x0;
        outb[n1] = x1;
        V0  = V1[(size_t)b * NU + n0];
        V1r = V1[(size_t)b * NU + n1];
        z0 = V0  > 1.0f;
        z1 = V1r > 1.0f;
        float* f1 = outb + NU;
        f1[n0] = z0 ? 1.0f : 0.0f;
        f1[n1] = z1 ? 1.0f : 0.0f;
        s_flag[n0] = (unsigned char)z0;
        s_flag[n1] = (unsigned char)z1;
    }
    __syncthreads();

    for (int t = 2; t < TSTEPS; ++t) {
        // ---- ascending spike index list (wave scan + wave offsets)
        int f0 = s_flag[2 * tid];
        int f1 = s_flag[2 * tid + 1];
        int c  = f0 + f1;
        int v  = c;
        #pragma unroll
        for (int d = 1; d < 64; d <<= 1) {
            int o = __shfl_up(v, d);
            if (lane >= d) v += o;
        }
        if (lane == 63) s_wsum[wid] = v;
        __syncthreads();
        int base = 0;
        #pragma unroll
        for (int w = 0; w < NWAVES; ++w) base += (w < wid) ? s_wsum[w] : 0;
        int off = base + v - c;                   // exclusive prefix
        if (f0) s_idx[off++] = (2 * tid) * NU;    // store row offset directly
        if (f1) s_idx[off]   = (2 * tid + 1) * NU;
        if (tid == BLK - 1) s_cnt = base + v;
        __syncthreads();

        int cnt = s_cnt;
        if (cnt == 0) {
            // dead network: all remaining frames exactly zero
            size_t  elems  = (size_t)(TSTEPS - t) * NU;
            float4* p      = (float4*)(outb + (size_t)t * NU);
            int     chunks = (int)(elems / 4);
            float4  zz; zz.x = zz.y = zz.z = zz.w = 0.0f;
            for (int i = tid; i < chunks; i += BLK) p[i] = zz;
            return;
        }

        // ---- sparse I: ordered fp32 adds over sorted spiking rows
        float I0 = 0.0f, I1 = 0.0f;
        const float* Wc = W + tid;
        int i = 0;
        for (; i + 4 <= cnt; i += 4) {
            const float* r0 = Wc + s_idx[i];
            const float* r1 = Wc + s_idx[i + 1];
            const float* r2 = Wc + s_idx[i + 2];
            const float* r3 = Wc + s_idx[i + 3];
            float a0 = r0[0], b0 = r0[BLK];
            float a1 = r1[0], b1 = r1[BLK];
            float a2 = r2[0], b2 = r2[BLK];
            float a3 = r3[0], b3 = r3[BLK];
            I0 += a0; I0 += a1; I0 += a2; I0 += a3;   // order preserved
            I1 += b0; I1 += b1; I1 += b2; I1 += b3;
        }
        for (; i < cnt; ++i) {
            const float* r = Wc + s_idx[i];
            I0 += r[0];
            I1 += r[BLK];
        }

        // ---- V update + threshold, op-by-op as the reference
        float d0 = 0.90483741803595952f * V0;     // one rounding
        float d1 = 0.90483741803595952f * V1r;
        asm volatile("" : "+v"(d0), "+v"(d1));    // forbid fma-contraction
        float nv0 = (z0 ? 0.0f : d0) + I0;        // one rounding
        float nv1 = (z1 ? 0.0f : d1) + I1;
        V0 = nv0; V1r = nv1;
        z0 = nv0 > 1.0f;
        z1 = nv1 > 1.0f;

        float* po = outb + (size_t)t * NU;
        po[n0] = z0 ? 1.0f : 0.0f;
        po[n1] = z1 ? 1.0f : 0.0f;
        s_flag[n0] = (unsigned char)z0;
        s_flag[n1] = (unsigned char)z1;
        __syncthreads();
    }
}

// ---------------- Fallback: round-4 fused kernel (proven, 320 us) ----------
__global__ __launch_bounds__(BLK) void lif_fused(
    const float* __restrict__ x,
    const float* __restrict__ W,
    float* __restrict__ out)
{
    const int b    = blockIdx.x;
    const int tid  = threadIdx.x;
    const int lane = tid & 63;
    const int wid  = tid >> 6;

    __shared__ float         s_x[NU];
    __shared__ int           s_idx[NU];
    __shared__ unsigned char s_flag[NU];
    __shared__ int           s_wsum[NWAVES];
    __shared__ int           s_cnt;

    const int n0 = tid;
    const int n1 = tid + BLK;
    float* outb = out + (size_t)b * TSTEPS * NU;

    {
        float x0 = x[(size_t)b * NU + n0];
        float x1 = x[(size_t)b * NU + n1];
        s_x[n0] = x0; s_x[n1] = x1;
        outb[n0] = x0; outb[n1] = x1;
    }
    __syncthreads();

    float I0 = 0.0f, I1 = 0.0f;
    {
        const float* Wc = W + tid;
        #pragma unroll 8
        for (int k = 0; k < NU; ++k) {
            float xk = s_x[k];
            const float* wr = Wc + (size_t)k * NU;
            I0 = __builtin_fmaf(xk, wr[0],   I0);
            I1 = __builtin_fmaf(xk, wr[BLK], I1);
        }
    }

    float V0 = 0.0f, V1 = 0.0f;
    int   z0 = 0,    z1 = 0;

    for (int t = 1; t < TSTEPS; ++t) {
        if (t >= 2) {
            int f0 = s_flag[2 * tid];
            int f1 = s_flag[2 * tid + 1];
            int c  = f0 + f1;
            int v  = c;
            #pragma unroll
            for (int d = 1; d < 64; d <<= 1) {
                int o = __shfl_up(v, d);
                if (lane >= d) v += o;
            }
            if (lane == 63) s_wsum[wid] = v;
            __syncthreads();
            int base = 0;
            #pragma unroll
            for (int w = 0; w < NWAVES; ++w) base += (w < wid) ? s_wsum[w] : 0;
            int off = base + v - c;
            if (f0) s_idx[off++] = 2 * tid;
            if (f1) s_idx[off]   = 2 * tid + 1;
            if (tid == BLK - 1) s_cnt = base + v;
            __syncthreads();

            int cnt = s_cnt;
            if (cnt == 0) {
                size_t  elems  = (size_t)(TSTEPS - t) * NU;
                float4* p      = (float4*)(outb + (size_t)t * NU);
                int     chunks = (int)(elems / 4);
                float4  zz; zz.x = zz.y = zz.z = zz.w = 0.0f;
                for (int i = tid; i < chunks; i += BLK) p[i] = zz;
                return;
            }

            I0 = 0.0f; I1 = 0.0f;
            const float* Wc = W + tid;
            int i = 0;
            for (; i + 2 <= cnt; i += 2) {
                const float* r0 = Wc + (size_t)s_idx[i]     * NU;
                const float* r1 = Wc + (size_t)s_idx[i + 1] * NU;
                float a0 = r0[0], b0 = r0[BLK];
                float a1 = r1[0], b1 = r1[BLK];
                I0 += a0; I0 += a1;
                I1 += b0; I1 += b1;
            }
            for (; i < cnt; ++i) {
                const float* r = Wc + (size_t)s_idx[i] * NU;
                I0 += r[0];
                I1 += r[BLK];
            }
        }

        float d0 = 0.90483741803595952f * V0;
        float d1 = 0.90483741803595952f * V1;
        asm volatile("" : "+v"(d0), "+v"(d1));
        float nv0 = (z0 ? 0.0f : d0) + I0;
        float nv1 = (z1 ? 0.0f : d1) + I1;
        V0 = nv0; V1 = nv1;
        z0 = nv0 > 1.0f;
        z1 = nv1 > 1.0f;

        float* po = outb + (size_t)t * NU;
        po[n0] = z0 ? 1.0f : 0.0f;
        po[n1] = z1 ? 1.0f : 0.0f;
        s_flag[n0] = (unsigned char)z0;
        s_flag[n1] = (unsigned char)z1;
        __syncthreads();
    }
}

extern "C" void kernel_launch(void* const* d_in, const int* in_sizes, int n_in,
                              void* d_out, int out_size, void* d_ws, size_t ws_size,
                              hipStream_t stream) {
    const float* x = (const float*)d_in[0];   // (256, 2048) fp32
    const float* W = (const float*)d_in[1];   // (2048, 2048) fp32
    if (n_in >= 2 && in_sizes[0] == NU * NU && in_sizes[1] == BATCHSZ * NU) {
        const float* t = x; x = W; W = t;     // defensive input-order swap
    }
    float* out = (float*)d_out;               // (B, T, N) fp32

    const size_t need = (size_t)BATCHSZ * NU * sizeof(float);   // 2 MB
    if (ws_size >= need) {
        float* V1 = (float*)d_ws;
        hipLaunchKernelGGL(lif_dense_v1,
                           dim3(NU / A_BN, BATCHSZ / A_BM), dim3(128), 0, stream,
                           x, W, V1);
        hipLaunchKernelGGL(lif_recurrence,
                           dim3(BATCHSZ), dim3(BLK), 0, stream,
                           x, W, V1, out);
    } else {
        hipLaunchKernelGGL(lif_fused, dim3(BATCHSZ), dim3(BLK), 0, stream,
                           x, W, out);
    }
}

// Round 6
// 209.594 us; speedup vs baseline: 1.2065x; 1.1851x over previous
//
#include <hip/hip_runtime.h>
#include <stdint.h>

// LIF spike encoder — two-phase, bit-exact fp32.
//   Round 4: fused, 320 us (PASS, absmax 0.0).
//   Round 5: split; dense phase landed at 243 us: 256 blocks x 128 thr =
//     0.5 waves/SIMD (Occupancy 5.8%, VALUBusy 7.5%) -> latency-starved, plus
//     8-way LDS conflicts on the transpose store. Recurrence phase ~5 us
//     in-graph. This round re-tiles the dense GEMM for occupancy:
//       block 256 thr, tile BM=8 x BN=128, per-thread 1 row x float4 cols,
//       grid 16x32 = 512 blocks -> 2 blocks/CU, 2 waves/SIMD;
//       whole x-rows staged in 64 KB LDS (one barrier, broadcast reads,
//       conflict-free); W read as coalesced float4, k ascending.
// Bit-exactness: every output element is ONE register accumulated by
// fmaf over k=0..2047 ascending -> identical chain to the passing kernels.

#define BATCHSZ 256
#define NU      2048
#define TSTEPS  128
#define BLK     1024
#define NWAVES  (BLK / 64)

// ---------------- Phase A: dense GEMM (t=1), bit-exact chain ----------------
// tile: BM=8 rows x BN=128 cols, 256 threads, per-thread 1 row x 4 cols.
#define A_BM 8
#define A_BN 128

__global__ __launch_bounds__(256) void lif_dense_v1(
    const float* __restrict__ x,
    const float* __restrict__ W,
    float* __restrict__ ws)
{
    __shared__ float s_x[A_BM][NU];          // 64 KB: the block's 8 x-rows

    const int tid = threadIdx.x;
    const int n0  = blockIdx.x * A_BN;
    const int m0  = blockIdx.y * A_BM;

    // ---- stage all 8 x-rows (coalesced float4), one barrier total
    {
        const int r = tid >> 5;              // 0..7
        const int l = tid & 31;              // 0..31
        const float* xr = x + (size_t)(m0 + r) * NU;
        #pragma unroll
        for (int j = 0; j < 16; ++j) {
            int col = l * 4 + j * 128;
            float4 v = *(const float4*)(xr + col);
            *(float4*)&s_x[r][col] = v;
        }
    }
    __syncthreads();

    const int mg    = tid >> 5;              // row within tile, 0..7
    const int nlane = tid & 31;              // col group, 0..31
    const int n     = n0 + nlane * 4;

    const float* xr = &s_x[mg][0];
    const float* wp = W + n;

    float4 acc; acc.x = acc.y = acc.z = acc.w = 0.0f;

    #pragma unroll 8
    for (int k = 0; k < NU; ++k) {
        float  xk = xr[k];                   // LDS broadcast (2-way, free)
        float4 wv = *(const float4*)(wp + (size_t)k * NU);
        acc.x = __builtin_fmaf(xk, wv.x, acc.x);
        acc.y = __builtin_fmaf(xk, wv.y, acc.y);
        acc.z = __builtin_fmaf(xk, wv.z, acc.z);
        acc.w = __builtin_fmaf(xk, wv.w, acc.w);
    }

    *(float4*)&ws[(size_t)(m0 + mg) * NU + n] = acc;
}

// ---------------- Phase B: recurrence from t=2 (unchanged, proven) ---------
__global__ __launch_bounds__(BLK) void lif_recurrence(
    const float* __restrict__ x,
    const float* __restrict__ W,
    const float* __restrict__ V1,
    float* __restrict__ out)
{
    const int b    = blockIdx.x;
    const int tid  = threadIdx.x;
    const int lane = tid & 63;
    const int wid  = tid >> 6;

    __shared__ int           s_idx[NU];      // spiking row offsets (k*NU)
    __shared__ unsigned char s_flag[NU];
    __shared__ int           s_wsum[NWAVES];
    __shared__ int           s_cnt;

    const int n0 = tid;
    const int n1 = tid + BLK;

    float* outb = out + (size_t)b * TSTEPS * NU;   // (B, T, N)

    float V0, V1r;
    int   z0, z1;
    {
        float x0 = x[(size_t)b * NU + n0];
        float x1 = x[(size_t)b * NU + n1];
        outb[n0] = x0;
        outb[n1] = x1;
        V0  = V1[(size_t)b * NU + n0];
        V1r = V1[(size_t)b * NU + n1];
        z0 = V0  > 1.0f;
        z1 = V1r > 1.0f;
        float* f1 = outb + NU;
        f1[n0] = z0 ? 1.0f : 0.0f;
        f1[n1] = z1 ? 1.0f : 0.0f;
        s_flag[n0] = (unsigned char)z0;
        s_flag[n1] = (unsigned char)z1;
    }
    __syncthreads();

    for (int t = 2; t < TSTEPS; ++t) {
        int f0 = s_flag[2 * tid];
        int f1 = s_flag[2 * tid + 1];
        int c  = f0 + f1;
        int v  = c;
        #pragma unroll
        for (int d = 1; d < 64; d <<= 1) {
            int o = __shfl_up(v, d);
            if (lane >= d) v += o;
        }
        if (lane == 63) s_wsum[wid] = v;
        __syncthreads();
        int base = 0;
        #pragma unroll
        for (int w = 0; w < NWAVES; ++w) base += (w < wid) ? s_wsum[w] : 0;
        int off = base + v - c;                   // exclusive prefix
        if (f0) s_idx[off++] = (2 * tid) * NU;
        if (f1) s_idx[off]   = (2 * tid + 1) * NU;
        if (tid == BLK - 1) s_cnt = base + v;
        __syncthreads();

        int cnt = s_cnt;
        if (cnt == 0) {
            size_t  elems  = (size_t)(TSTEPS - t) * NU;
            float4* p      = (float4*)(outb + (size_t)t * NU);
            int     chunks = (int)(elems / 4);
            float4  zz; zz.x = zz.y = zz.z = zz.w = 0.0f;
            for (int i = tid; i < chunks; i += BLK) p[i] = zz;
            return;
        }

        float I0 = 0.0f, I1 = 0.0f;
        const float* Wc = W + tid;
        int i = 0;
        for (; i + 4 <= cnt; i += 4) {
            const float* r0 = Wc + s_idx[i];
            const float* r1 = Wc + s_idx[i + 1];
            const float* r2 = Wc + s_idx[i + 2];
            const float* r3 = Wc + s_idx[i + 3];
            float a0 = r0[0], b0 = r0[BLK];
            float a1 = r1[0], b1 = r1[BLK];
            float a2 = r2[0], b2 = r2[BLK];
            float a3 = r3[0], b3 = r3[BLK];
            I0 += a0; I0 += a1; I0 += a2; I0 += a3;   // order preserved
            I1 += b0; I1 += b1; I1 += b2; I1 += b3;
        }
        for (; i < cnt; ++i) {
            const float* r = Wc + s_idx[i];
            I0 += r[0];
            I1 += r[BLK];
        }

        float d0 = 0.90483741803595952f * V0;     // one rounding
        float d1 = 0.90483741803595952f * V1r;
        asm volatile("" : "+v"(d0), "+v"(d1));    // forbid fma-contraction
        float nv0 = (z0 ? 0.0f : d0) + I0;        // one rounding
        float nv1 = (z1 ? 0.0f : d1) + I1;
        V0 = nv0; V1r = nv1;
        z0 = nv0 > 1.0f;
        z1 = nv1 > 1.0f;

        float* po = outb + (size_t)t * NU;
        po[n0] = z0 ? 1.0f : 0.0f;
        po[n1] = z1 ? 1.0f : 0.0f;
        s_flag[n0] = (unsigned char)z0;
        s_flag[n1] = (unsigned char)z1;
        __syncthreads();
    }
}

// ---------------- Fallback: round-4 fused kernel (proven) ------------------
__global__ __launch_bounds__(BLK) void lif_fused(
    const float* __restrict__ x,
    const float* __restrict__ W,
    float* __restrict__ out)
{
    const int b    = blockIdx.x;
    const int tid  = threadIdx.x;
    const int lane = tid & 63;
    const int wid  = tid >> 6;

    __shared__ float         s_x[NU];
    __shared__ int           s_idx[NU];
    __shared__ unsigned char s_flag[NU];
    __shared__ int           s_wsum[NWAVES];
    __shared__ int           s_cnt;

    const int n0 = tid;
    const int n1 = tid + BLK;
    float* outb = out + (size_t)b * TSTEPS * NU;

    {
        float x0 = x[(size_t)b * NU + n0];
        float x1 = x[(size_t)b * NU + n1];
        s_x[n0] = x0; s_x[n1] = x1;
        outb[n0] = x0; outb[n1] = x1;
    }
    __syncthreads();

    float I0 = 0.0f, I1 = 0.0f;
    {
        const float* Wc = W + tid;
        #pragma unroll 8
        for (int k = 0; k < NU; ++k) {
            float xk = s_x[k];
            const float* wr = Wc + (size_t)k * NU;
            I0 = __builtin_fmaf(xk, wr[0],   I0);
            I1 = __builtin_fmaf(xk, wr[BLK], I1);
        }
    }

    float V0 = 0.0f, V1 = 0.0f;
    int   z0 = 0,    z1 = 0;

    for (int t = 1; t < TSTEPS; ++t) {
        if (t >= 2) {
            int f0 = s_flag[2 * tid];
            int f1 = s_flag[2 * tid + 1];
            int c  = f0 + f1;
            int v  = c;
            #pragma unroll
            for (int d = 1; d < 64; d <<= 1) {
                int o = __shfl_up(v, d);
                if (lane >= d) v += o;
            }
            if (lane == 63) s_wsum[wid] = v;
            __syncthreads();
            int base = 0;
            #pragma unroll
            for (int w = 0; w < NWAVES; ++w) base += (w < wid) ? s_wsum[w] : 0;
            int off = base + v - c;
            if (f0) s_idx[off++] = 2 * tid;
            if (f1) s_idx[off]   = 2 * tid + 1;
            if (tid == BLK - 1) s_cnt = base + v;
            __syncthreads();

            int cnt = s_cnt;
            if (cnt == 0) {
                size_t  elems  = (size_t)(TSTEPS - t) * NU;
                float4* p      = (float4*)(outb + (size_t)t * NU);
                int     chunks = (int)(elems / 4);
                float4  zz; zz.x = zz.y = zz.z = zz.w = 0.0f;
                for (int i = tid; i < chunks; i += BLK) p[i] = zz;
                return;
            }

            I0 = 0.0f; I1 = 0.0f;
            const float* Wc = W + tid;
            int i = 0;
            for (; i + 2 <= cnt; i += 2) {
                const float* r0 = Wc + (size_t)s_idx[i]     * NU;
                const float* r1 = Wc + (size_t)s_idx[i + 1] * NU;
                float a0 = r0[0], b0 = r0[BLK];
                float a1 = r1[0], b1 = r1[BLK];
                I0 += a0; I0 += a1;
                I1 += b0; I1 += b1;
            }
            for (; i < cnt; ++i) {
                const float* r = Wc + (size_t)s_idx[i] * NU;
                I0 += r[0];
                I1 += r[BLK];
            }
        }

        float d0 = 0.90483741803595952f * V0;
        float d1 = 0.90483741803595952f * V1;
        asm volatile("" : "+v"(d0), "+v"(d1));
        float nv0 = (z0 ? 0.0f : d0) + I0;
        float nv1 = (z1 ? 0.0f : d1) + I1;
        V0 = nv0; V1 = nv1;
        z0 = nv0 > 1.0f;
        z1 = nv1 > 1.0f;

        float* po = outb + (size_t)t * NU;
        po[n0] = z0 ? 1.0f : 0.0f;
        po[n1] = z1 ? 1.0f : 0.0f;
        s_flag[n0] = (unsigned char)z0;
        s_flag[n1] = (unsigned char)z1;
        __syncthreads();
    }
}

extern "C" void kernel_launch(void* const* d_in, const int* in_sizes, int n_in,
                              void* d_out, int out_size, void* d_ws, size_t ws_size,
                              hipStream_t stream) {
    const float* x = (const float*)d_in[0];   // (256, 2048) fp32
    const float* W = (const float*)d_in[1];   // (2048, 2048) fp32
    if (n_in >= 2 && in_sizes[0] == NU * NU && in_sizes[1] == BATCHSZ * NU) {
        const float* t = x; x = W; W = t;     // defensive input-order swap
    }
    float* out = (float*)d_out;               // (B, T, N) fp32

    const size_t need = (size_t)BATCHSZ * NU * sizeof(float);   // 2 MB
    if (ws_size >= need) {
        float* V1 = (float*)d_ws;
        hipLaunchKernelGGL(lif_dense_v1,
                           dim3(NU / A_BN, BATCHSZ / A_BM), dim3(256), 0, stream,
                           x, W, V1);
        hipLaunchKernelGGL(lif_recurrence,
                           dim3(BATCHSZ), dim3(BLK), 0, stream,
                           x, W, V1, out);
    } else {
        hipLaunchKernelGGL(lif_fused, dim3(BATCHSZ), dim3(BLK), 0, stream,
                           x, W, out);
    }
}